// Round 14
// baseline (75.379 us; speedup 1.0000x reference)
//
#include <hip/hip_runtime.h>
#include <hip/hip_bf16.h>
#include <math.h>

#define W_  160
#define H_  128
#define HW  20480
#define D_  48
#define C_  32
#define NV  4    // source views (views 1..4)

// conv tile
#define TX  16
#define TY  4
#define TXH 18
#define TYH 6
#define NCOL (TXH*TYH)   // 108
#define GD  4            // depth groups
#define GDS 12           // depths per group

// ---------------- cross-lane helpers ----------------
// 0xB1 = quad_perm [1,0,3,2] (xor 1); 0x4E = quad_perm [2,3,0,1] (xor 2);
// 0x141 = row_half_mirror: after xor1+xor2 each quad holds its quad-sum,
// half-mirror adds the sibling quad -> full 8-lane sum in all 8 lanes.
template<int CTRL>
__device__ __forceinline__ float dpp_add(float s) {
  int t = __builtin_amdgcn_update_dpp(0, __float_as_int(s), CTRL, 0xF, 0xF, true);
  return s + __int_as_float(t);
}

// monotone float<->uint ordering (for atomic max)
__device__ __forceinline__ unsigned ordf(float f) {
  unsigned b = __float_as_uint(f);
  return b ^ (((int)b >> 31) | 0x80000000u);
}
__device__ __forceinline__ float deordf(unsigned u) {
  unsigned b = (u & 0x80000000u) ? (u ^ 0x80000000u) : ~u;
  return __uint_as_float(b);
}

// ---------------- projection helpers ----------------
__device__ __forceinline__ void fuse_proj(const float* pm, float* P) {
  const float* E = pm;
  const float* K = pm + 16;
  for (int r = 0; r < 3; ++r)
    for (int c = 0; c < 4; ++c)
      P[r*4+c] = K[r*4+0]*E[0*4+c] + K[r*4+1]*E[1*4+c] + K[r*4+2]*E[2*4+c];
  for (int c = 0; c < 4; ++c) P[12+c] = E[12+c];
}

__device__ void invert4(const float* m, float* invOut) {
  float inv[16];
  inv[0]  =  m[5]*m[10]*m[15] - m[5]*m[11]*m[14] - m[9]*m[6]*m[15] + m[9]*m[7]*m[14] + m[13]*m[6]*m[11] - m[13]*m[7]*m[10];
  inv[4]  = -m[4]*m[10]*m[15] + m[4]*m[11]*m[14] + m[8]*m[6]*m[15] - m[8]*m[7]*m[14] - m[12]*m[6]*m[11] + m[12]*m[7]*m[10];
  inv[8]  =  m[4]*m[9]*m[15]  - m[4]*m[11]*m[13] - m[8]*m[5]*m[15] + m[8]*m[7]*m[13] + m[12]*m[5]*m[11] - m[12]*m[7]*m[9];
  inv[12] = -m[4]*m[9]*m[14]  + m[4]*m[10]*m[13] + m[8]*m[5]*m[14] - m[8]*m[6]*m[13] - m[12]*m[5]*m[10] + m[12]*m[6]*m[9];
  inv[1]  = -m[1]*m[10]*m[15] + m[1]*m[11]*m[14] + m[9]*m[2]*m[15] - m[9]*m[3]*m[14] - m[13]*m[2]*m[11] + m[13]*m[3]*m[10];
  inv[5]  =  m[0]*m[10]*m[15] - m[0]*m[11]*m[14] - m[8]*m[2]*m[15] + m[8]*m[3]*m[14] + m[12]*m[2]*m[11] - m[12]*m[3]*m[10];
  inv[9]  = -m[0]*m[9]*m[15]  + m[0]*m[11]*m[13] + m[8]*m[1]*m[15] - m[8]*m[3]*m[13] - m[12]*m[1]*m[11] + m[12]*m[3]*m[9];
  inv[13] =  m[0]*m[9]*m[14]  - m[0]*m[10]*m[13] - m[8]*m[1]*m[14] + m[8]*m[2]*m[13] + m[12]*m[1]*m[10] - m[12]*m[2]*m[9];
  inv[2]  =  m[1]*m[6]*m[15]  - m[1]*m[7]*m[14]  - m[5]*m[2]*m[15] + m[5]*m[3]*m[14] + m[13]*m[2]*m[7]  - m[13]*m[3]*m[6];
  inv[6]  = -m[0]*m[6]*m[15]  + m[0]*m[7]*m[14]  + m[4]*m[2]*m[15] - m[4]*m[3]*m[14] - m[12]*m[2]*m[7]  + m[12]*m[3]*m[6];
  inv[10] =  m[0]*m[5]*m[15]  - m[0]*m[7]*m[13]  - m[4]*m[1]*m[15] + m[4]*m[3]*m[13] + m[12]*m[1]*m[7]  - m[12]*m[3]*m[5];
  inv[14] = -m[0]*m[5]*m[14]  + m[0]*m[6]*m[13]  + m[4]*m[1]*m[14] - m[4]*m[2]*m[13] - m[12]*m[1]*m[6]  + m[12]*m[2]*m[5];
  inv[3]  = -m[1]*m[6]*m[11]  + m[1]*m[7]*m[10]  + m[5]*m[2]*m[11] - m[5]*m[3]*m[10] - m[9]*m[2]*m[7]   + m[9]*m[3]*m[6];
  inv[7]  =  m[0]*m[6]*m[11]  - m[0]*m[7]*m[10]  - m[4]*m[2]*m[11] + m[4]*m[3]*m[10] + m[8]*m[2]*m[7]   - m[8]*m[3]*m[6];
  inv[11] = -m[0]*m[5]*m[11]  + m[0]*m[7]*m[9]   + m[4]*m[1]*m[11] - m[4]*m[3]*m[9]  - m[8]*m[1]*m[7]   + m[8]*m[3]*m[5];
  inv[15] =  m[0]*m[5]*m[10]  - m[0]*m[6]*m[9]   - m[4]*m[1]*m[10] + m[4]*m[2]*m[9]  + m[8]*m[1]*m[6]   - m[8]*m[2]*m[5];
  float det = m[0]*inv[0] + m[1]*inv[4] + m[2]*inv[8] + m[3]*inv[12];
  det = 1.0f / det;
  for (int i = 0; i < 16; i++) invOut[i] = inv[i] * det;
}

// ---------------- prep: transpose + xform + zero pads/accumulators ---------
__global__ void __launch_bounds__(256)
k_prep(const float* __restrict__ feat, const float* __restrict__ pm,
       float* __restrict__ tf, float* __restrict__ xf,
       unsigned* __restrict__ vwu) {
  __shared__ float tile[C_][64+1];
  int v  = blockIdx.y;
  int p0 = blockIdx.x * 64;
  int t  = threadIdx.x;

  if (v == 0) vwu[blockIdx.x*256 + t] = 0u;

  int pl = t & 63;
  int cg = t >> 6;            // 0..3
  const float* src = feat + (size_t)v*C_*HW + p0 + pl;
  #pragma unroll
  for (int k = 0; k < 8; ++k) {
    int c = cg*8 + k;
    tile[c][pl] = src[(size_t)c*HW];
  }
  __syncthreads();

  int pp = t >> 2;            // pixel 0..63
  int co = (t & 3) * 8;       // channel offset
  float4 a, b;
  a.x = tile[co+0][pp]; a.y = tile[co+1][pp]; a.z = tile[co+2][pp]; a.w = tile[co+3][pp];
  b.x = tile[co+4][pp]; b.y = tile[co+5][pp]; b.z = tile[co+6][pp]; b.w = tile[co+7][pp];
  float* dst = tf + ((size_t)v*HW + p0 + pp)*C_ + co;
  *(float4*)dst = a;
  *(float4*)(dst+4) = b;

  if (blockIdx.x == 0 && v == 0) {
    if (t < 64) tf[(size_t)5*HW*C_ + t] = 0.0f;   // zero pad (invalid corners)
    if (t == 0) {
      float Pr[16], Pinv[16], Ps[16], M[16];
      fuse_proj(pm, Pr);
      invert4(Pr, Pinv);
      for (int vv = 1; vv <= NV; ++vv) {
        fuse_proj(pm + vv*32, Ps);
        for (int r = 0; r < 4; ++r)
          for (int c = 0; c < 4; ++c) {
            float acc = 0.f;
            for (int k = 0; k < 4; ++k) acc += Ps[r*4+k]*Pinv[k*4+c];
            M[r*4+c] = acc;
          }
        float* o = xf + (vv-1)*12;
        o[0]=M[0];  o[1]=M[1];  o[2]=M[2];
        o[3]=M[4];  o[4]=M[5];  o[5]=M[6];
        o[6]=M[8];  o[7]=M[9];  o[8]=M[10];
        o[9]=M[3];  o[10]=M[7]; o[11]=M[11];
      }
    }
  }
}

// ---------------- texel-dot table builder (fast path) ----------------
template<int KX>
__device__ __forceinline__ void build_tab(
    const char* tfb, int chb, int ZB, float4 rfc,
    int xmin, int ymin, int ch, float* tabp) {
  #pragma unroll
  for (int t = 0; t < KX*3; ++t) {
    int xi = xmin + t/3;
    int yi = ymin + t%3;
    bool valid = ((unsigned)xi < (unsigned)W_) && ((unsigned)yi < (unsigned)H_);
    int off = valid ? (yi*W_ + xi)*(C_*4) : ZB;
    float4 a = *(const float4*)(tfb + off + chb);
    float d = a.x*rfc.x + a.y*rfc.y + a.z*rfc.z + a.w*rfc.w;
    d = dpp_add<0xB1>(d);
    d = dpp_add<0x4E>(d);
    d = dpp_add<0x141>(d);
    if (ch == (t & 7)) tabp[t] = d;
  }
}

// ---------------- main warp + similarity kernel (R13, unchanged) ----------
__global__ void __launch_bounds__(256)
k_warp(const float* __restrict__ tf, const float* __restrict__ dv,
       const float* __restrict__ xf, float* __restrict__ sim_all) {
  __shared__ float dtab[4][8][25];

  int lane = threadIdx.x & 63;
  int wv = threadIdx.x >> 6;
  int ch = lane & 7;
  int pix = (lane >> 3) & 7;
  int wvg = __builtin_amdgcn_readfirstlane((blockIdx.x*256 + threadIdx.x) >> 6);
  const int PGPV = HW/8;
  int pg = wvg % PGPV;
  int v  = wvg / PGPV;
  int p  = pg*8 + pix;

  float xpix = (float)(p % W_);
  float ypix = (float)(p / W_);

  const float* M = xf + v*12;
  float rx = M[0]*xpix + M[1]*ypix + M[2];
  float ry = M[3]*xpix + M[4]*ypix + M[5];
  float rz = M[6]*xpix + M[7]*ypix + M[8];
  float t0 = M[9], t1 = M[10], t2 = M[11];

  float4 rfc = *(const float4*)(tf + (size_t)p*C_ + ch*4);
  rfc.x *= (1.0f/(float)C_); rfc.y *= (1.0f/(float)C_);
  rfc.z *= (1.0f/(float)C_); rfc.w *= (1.0f/(float)C_);

  const char* tfb = (const char*)(tf + (size_t)(v+1)*HW*C_);
  const int chb = ch*16;
  const int ZB = (4-v)*HW*C_*4;

  float depE0 = dv[p];
  float depE1 = dv[(size_t)47*HW + p];
  float dpk[6];
  #pragma unroll
  for (int k = 0; k < 6; ++k) dpk[k] = dv[(size_t)(k*8 + ch)*HW + p];

  float Z0 = rz*depE0 + t2, Z1 = rz*depE1 + t2;
  float iz0 = 1.0f / Z0,     iz1 = 1.0f / Z1;
  float pxa = (rx*depE0 + t0) * iz0, pya = (ry*depE0 + t1) * iz0;
  float pxb = (rx*depE1 + t0) * iz1, pyb = (ry*depE1 + t1) * iz1;
  int xmin = (int)floorf(fminf(pxa, pxb));
  int ymin = (int)floorf(fminf(pya, pyb));
  int Nx = (int)floorf(fmaxf(pxa, pxb)) - xmin + 2;
  int Ny = (int)floorf(fmaxf(pya, pyb)) - ymin + 2;

  float dmn = fminf(depE0, depE1), dmx = fmaxf(depE0, depE1);
  bool ok = (Nx <= 8) && (Ny <= 3) && (Z0*Z1 > 0.0f);
  #pragma unroll
  for (int k = 0; k < 6; ++k) ok = ok && (dpk[k] >= dmn) && (dpk[k] <= dmx);

  float* simv = sim_all + (size_t)v*D_*HW + p;

  if (__all(ok)) {
    float* tabp = dtab[wv][pix];
    if (__all(Nx <= 5)) build_tab<5>(tfb, chb, ZB, rfc, xmin, ymin, ch, tabp);
    else                build_tab<8>(tfb, chb, ZB, rfc, xmin, ymin, ch, tabp);

    int xhi = xmin + 6;
    if (__all(Nx <= 5)) xhi = xmin + 3;

    #pragma unroll
    for (int k = 0; k < 6; ++k) {
      float dep = dpk[k];
      float Z  = rz*dep + t2;
      float zr = 1.0f / Z;
      float px = (rx*dep + t0) * zr;
      float py = (ry*dep + t1) * zr;
      int xi = (int)floorf(px);
      int yi = (int)floorf(py);
      xi = min(max(xi, xmin), xhi);
      yi = min(max(yi, ymin), ymin + 1);
      float wx1 = px - (float)xi;
      float wy1 = py - (float)yi;
      float wx0 = 1.0f - wx1, wy0 = 1.0f - wy1;
      int idx = (xi - xmin)*3 + (yi - ymin);
      float t00 = tabp[idx];
      float t01 = tabp[idx + 3];
      float t10 = tabp[idx + 1];
      float t11 = tabp[idx + 4];
      float s = wx0*wy0*t00 + wx1*wy0*t01 + wx0*wy1*t10 + wx1*wy1*t11;
      simv[(size_t)(k*8 + ch)*HW] = s;
    }
  } else {
    const float* tff  = tf + (size_t)(v+1)*HW*C_;
    const float* refp = tf + (size_t)p*C_;
    const int ZE = (4-v)*HW*C_;
    #pragma unroll 1
    for (int k = 0; k < 6; ++k) {
      float dep = dpk[k];
      float Z  = rz*dep + t2;
      float px = (rx*dep + t0) / Z;
      float py = (ry*dep + t1) / Z;
      float x0f = floorf(px), y0f = floorf(py);
      float wx1 = px - x0f, wy1 = py - y0f;
      float wx0 = 1.0f - wx1, wy0 = 1.0f - wy1;
      int x0 = (int)x0f, y0 = (int)y0f;
      int x1 = x0 + 1,   y1 = y0 + 1;
      bool vx0 = ((unsigned)x0 <= (unsigned)(W_-1));
      bool vx1 = ((unsigned)x1 <= (unsigned)(W_-1));
      bool vy0 = ((unsigned)y0 <= (unsigned)(H_-1));
      bool vy1 = ((unsigned)y1 <= (unsigned)(H_-1));
      int cx0 = min(max(x0, 0), W_-1);
      int cx1 = min(max(x1, 0), W_-1);
      int cy0 = min(max(y0, 0), H_-1);
      int cy1 = min(max(y1, 0), H_-1);
      int o00 = (vx0 && vy0) ? (cy0*W_+cx0)*C_ : ZE;
      int o01 = (vx1 && vy0) ? (cy0*W_+cx1)*C_ : ZE;
      int o10 = (vx0 && vy1) ? (cy1*W_+cx0)*C_ : ZE;
      int o11 = (vx1 && vy1) ? (cy1*W_+cx1)*C_ : ZE;
      float a00=0.f, a01=0.f, a10=0.f, a11=0.f;
      #pragma unroll 1
      for (int q = 0; q < 8; ++q) {
        float4 rq = *(const float4*)(refp + q*4);
        float4 c0 = *(const float4*)(tff + o00 + q*4);
        float4 c1 = *(const float4*)(tff + o01 + q*4);
        float4 c2 = *(const float4*)(tff + o10 + q*4);
        float4 c3 = *(const float4*)(tff + o11 + q*4);
        a00 += c0.x*rq.x + c0.y*rq.y + c0.z*rq.z + c0.w*rq.w;
        a01 += c1.x*rq.x + c1.y*rq.y + c1.z*rq.z + c1.w*rq.w;
        a10 += c2.x*rq.x + c2.y*rq.y + c2.z*rq.z + c2.w*rq.w;
        a11 += c3.x*rq.x + c3.y*rq.y + c3.z*rq.z + c3.w*rq.w;
      }
      float s = (wx0*wy0*a00 + wx1*wy0*a01 + wx0*wy1*a10 + wx1*wy1*a11)
                * (1.0f/(float)C_);
      simv[(size_t)(k*8 + ch)*HW] = s;
    }
  }
}

// ---------------- MLP: 4 depths per thread, atomic-max logit -------------
__global__ void __launch_bounds__(256)
k_mlp(const float* __restrict__ sim_all,
      const float* __restrict__ w0, const float* __restrict__ b0,
      const float* __restrict__ w1, const float* __restrict__ b1,
      const float* __restrict__ w2, const float* __restrict__ b2,
      unsigned* __restrict__ vwu) {
  int idx = blockIdx.x*blockDim.x + threadIdx.x;
  if (idx >= NV*(D_/4)*HW) return;
  int p = idx % HW;
  int t = idx / HW;           // (v, chunk)
  int v = t / (D_/4);
  int c = t % (D_/4);

  const float* sp_ = sim_all + ((size_t)(v*D_ + c*4))*HW + p;
  float sv[4];
  sv[0] = sp_[0];
  sv[1] = sp_[HW];
  sv[2] = sp_[2*HW];
  sv[3] = sp_[3*HW];

  float ymax = -3.0e38f;
  #pragma unroll
  for (int k = 0; k < 4; ++k) {
    float s = sv[k];
    float acc0 = b1[0], acc1 = b1[1], acc2 = b1[2], acc3 = b1[3];
    float acc4 = b1[4], acc5 = b1[5], acc6 = b1[6], acc7 = b1[7];
    #pragma unroll
    for (int o = 0; o < 16; ++o) {
      float h = fmaxf(fmaf(w0[o], s, b0[o]), 0.0f);
      acc0 = fmaf(w1[0*16+o], h, acc0);
      acc1 = fmaf(w1[1*16+o], h, acc1);
      acc2 = fmaf(w1[2*16+o], h, acc2);
      acc3 = fmaf(w1[3*16+o], h, acc3);
      acc4 = fmaf(w1[4*16+o], h, acc4);
      acc5 = fmaf(w1[5*16+o], h, acc5);
      acc6 = fmaf(w1[6*16+o], h, acc6);
      acc7 = fmaf(w1[7*16+o], h, acc7);
    }
    float yv = b2[0];
    yv = fmaf(w2[0], fmaxf(acc0, 0.0f), yv);
    yv = fmaf(w2[1], fmaxf(acc1, 0.0f), yv);
    yv = fmaf(w2[2], fmaxf(acc2, 0.0f), yv);
    yv = fmaf(w2[3], fmaxf(acc3, 0.0f), yv);
    yv = fmaf(w2[4], fmaxf(acc4, 0.0f), yv);
    yv = fmaf(w2[5], fmaxf(acc5, 0.0f), yv);
    yv = fmaf(w2[6], fmaxf(acc6, 0.0f), yv);
    yv = fmaf(w2[7], fmaxf(acc7, 0.0f), yv);
    ymax = fmaxf(ymax, yv);
  }
  atomicMax(&vwu[(size_t)v*HW + p], ordf(ymax));
}

// ---------------- fuse + 3x3x3 conv, depth-split for parallelism ----------
// grid (W/TX, H/TY, GD) = 1280 blocks, ~9.3 KB LDS -> high occupancy.
// Each block: builds 14 fused slices (12 own + 2 halo) for its 18x6 column
// window, then convolves its 12 depths x 64 pixels, writing cost to global.
__global__ void __launch_bounds__(256)
k_fusecv(const float* __restrict__ sim_all, const unsigned* __restrict__ vwu,
         const float* __restrict__ rw, const float* __restrict__ rb,
         float* __restrict__ cost) {
  __shared__ float svw[NV][NCOL];
  __shared__ float sinvw[NCOL];
  __shared__ int   sgpc[NCOL];
  __shared__ float sfus[GDS+2][TYH][TXH+1];

  int tid = threadIdx.x;
  int gx0 = blockIdx.x*TX;
  int gy0 = blockIdx.y*TY;
  int g   = blockIdx.z;

  // phase A: per-column view weights (decode + sigmoid) / inv wsum / pixel idx
  if (tid < NCOL) {
    int yy = tid / TXH, xx = tid % TXH;
    int gy = gy0 + yy - 1, gx = gx0 + xx - 1;
    bool valid = (gx >= 0) && (gx < W_) && (gy >= 0) && (gy < H_);
    int gp = min(max(gy,0),H_-1)*W_ + min(max(gx,0),W_-1);
    sgpc[tid] = gp;
    float a0 = 1.0f/(1.0f + expf(-deordf(vwu[0*HW+gp])));
    float a1 = 1.0f/(1.0f + expf(-deordf(vwu[1*HW+gp])));
    float a2 = 1.0f/(1.0f + expf(-deordf(vwu[2*HW+gp])));
    float a3 = 1.0f/(1.0f + expf(-deordf(vwu[3*HW+gp])));
    float inv = valid ? 1.0f/(1e-5f + a0+a1+a2+a3) : 0.0f;
    if (!valid) { a0=a1=a2=a3=0.f; }
    svw[0][tid]=a0; svw[1][tid]=a1; svw[2][tid]=a2; svw[3][tid]=a3;
    sinvw[tid] = inv;
  }
  __syncthreads();

  // phase B: fused slices dz in [g*12-1, g*12+12] (zero outside [0,48))
  for (int j = tid; j < (GDS+2)*NCOL; j += 256) {
    int s = j / NCOL, r = j % NCOL;
    int dz = g*GDS - 1 + s;
    float val = 0.0f;
    if (dz >= 0 && dz < D_) {
      int gp = sgpc[r];
      float s0 = sim_all[(size_t)(0*D_+dz)*HW + gp];
      float s1 = sim_all[(size_t)(1*D_+dz)*HW + gp];
      float s2 = sim_all[(size_t)(2*D_+dz)*HW + gp];
      float s3 = sim_all[(size_t)(3*D_+dz)*HW + gp];
      val = (s0*svw[0][r] + s1*svw[1][r] + s2*svw[2][r] + s3*svw[3][r]) * sinvw[r];
    }
    sfus[s][r/TXH][r%TXH] = val;
  }
  __syncthreads();

  // phase C: conv; thread = (pixel, 3 depths)
  {
    int pid = tid & 63;
    int dg  = tid >> 6;
    int px = pid & 15, py = pid >> 4;
    float kw[27];
    #pragma unroll
    for (int i = 0; i < 27; ++i) kw[i] = rw[i];
    float bias = rb[0];
    int gp = (gy0+py)*W_ + gx0+px;

    #pragma unroll
    for (int k = 0; k < 3; ++k) {
      int dl = dg*3 + k;         // 0..11 within group
      float acc = bias;
      #pragma unroll
      for (int kd = 0; kd < 3; ++kd)
        #pragma unroll
        for (int ky = 0; ky < 3; ++ky)
          #pragma unroll
          for (int kx = 0; kx < 3; ++kx)
            acc += sfus[dl+kd][py+ky][px+kx] * kw[(kd*3+ky)*3+kx];
      cost[(size_t)(g*GDS + dl)*HW + gp] = acc;
    }
  }
}

// ---------------- softmax / argmax / outputs, one thread per pixel --------
__global__ void __launch_bounds__(256)
k_softmax(const float* __restrict__ cost, const unsigned* __restrict__ vwu,
          const float* __restrict__ dv, float* __restrict__ out) {
  int p = blockIdx.x*256 + threadIdx.x;
  if (p >= HW) return;

  float c[D_];
  #pragma unroll
  for (int d = 0; d < D_; ++d) c[d] = cost[(size_t)d*HW + p];

  float vmax = c[0];
  int am = 0;
  #pragma unroll
  for (int d = 1; d < D_; ++d) {
    if (c[d] > vmax) { vmax = c[d]; am = d; }
  }
  float sum = 0.0f;
  #pragma unroll
  for (int d = 0; d < D_; ++d) {
    float e = expf(c[d] - vmax);
    c[d] = e;
    sum += e;
  }
  float inv = 1.0f / sum;
  #pragma unroll
  for (int d = 0; d < D_; ++d)
    out[(size_t)(2*HW) + (size_t)d*HW + p] = c[d] * inv;

  out[p] = dv[(size_t)am*HW + p];
  out[HW + p] = inv;
  #pragma unroll
  for (int v = 0; v < NV; ++v)
    out[(size_t)(2*HW + D_*HW) + (size_t)v*HW + p] =
        1.0f/(1.0f + expf(-deordf(vwu[(size_t)v*HW + p])));
}

// ---------------- launch ----------------
extern "C" void kernel_launch(void* const* d_in, const int* in_sizes, int n_in,
                              void* d_out, int out_size, void* d_ws, size_t ws_size,
                              hipStream_t stream) {
  const float* feat = (const float*)d_in[0];
  const float* pm   = (const float*)d_in[1];
  const float* dv   = (const float*)d_in[2];
  const float* w0   = (const float*)d_in[3];
  const float* b0   = (const float*)d_in[4];
  const float* w1   = (const float*)d_in[5];
  const float* b1   = (const float*)d_in[6];
  const float* w2   = (const float*)d_in[7];
  const float* b2   = (const float*)d_in[8];
  const float* rw   = (const float*)d_in[9];
  const float* rb   = (const float*)d_in[10];
  float* out = (float*)d_out;
  float* ws  = (float*)d_ws;

  // workspace layout (floats)
  float*    xf   = ws;                        // 48 (pad 64)
  float*    tf   = ws + 64;                   // 5*HW*C + 64 zero-pad
  float*    sim  = ws + 3276928;              // 4*48*HW = 3,932,160
  unsigned* vwu  = (unsigned*)(ws + 7209088); // 4*HW = 81,920
  float*    cost = ws + 7291008;              // 48*HW = 983,040
  // high-water mark: ~8.27M floats = ~33 MB

  hipLaunchKernelGGL(k_prep, dim3(HW/64, 5), dim3(256), 0, stream,
                     feat, pm, tf, xf, vwu);
  hipLaunchKernelGGL(k_warp, dim3((NV*HW*8)/256), dim3(256), 0, stream,
                     tf, dv, xf, sim);
  hipLaunchKernelGGL(k_mlp, dim3((NV*(D_/4)*HW)/256), dim3(256), 0, stream,
                     sim, w0, b0, w1, b1, w2, b2, vwu);
  hipLaunchKernelGGL(k_fusecv, dim3(W_/TX, H_/TY, GD), dim3(256), 0, stream,
                     sim, vwu, rw, rb, cost);
  hipLaunchKernelGGL(k_softmax, dim3(HW/256), dim3(256), 0, stream,
                     cost, vwu, dv, out);
}